// Round 12
// baseline (95.490 us; speedup 1.0000x reference)
//
#include <hip/hip_runtime.h>
#include <hip/hip_bf16.h>

#define SEQ    2048
#define DMODEL 1024
#define NHEADS 16
#define HD     64
#define CS     64
#define NC     (SEQ / CS)
#define STSZ   (HD * HD + HD)   // 4160 bf16: KVT[64][64] + ksum[64]
#define EPS_LA 1e-5f
#define LP     72               // padded LDS row stride (bf16 elems)
#define CLP    136              // epilogue repack stride (16B-aligned rows)

typedef __attribute__((ext_vector_type(8))) short  bf16x8;
typedef __attribute__((ext_vector_type(8))) unsigned short ushort8;
typedef __attribute__((ext_vector_type(4))) float  f32x4;

__device__ __forceinline__ void gload_lds16(const void* g, void* l) {
  __builtin_amdgcn_global_load_lds(
      (const __attribute__((address_space(1))) void*)g,
      (__attribute__((address_space(3))) void*)l, 16, 0, 0);
}

__device__ __forceinline__ ushort f2bf(float x) {
  __hip_bfloat16 h = __float2bfloat16(x);
  return __builtin_bit_cast(ushort, h);
}
__device__ __forceinline__ float bf2f(ushort u) {
  unsigned int v = ((unsigned int)u) << 16;
  return __builtin_bit_cast(float, v);
}

// ---------------------------------------------------------------------------
// Fused prep: blocks [0,4096) convert x f32->bf16; [4096,4864) transpose wqkv
// -> wqkvT (3072x1024); [4864,5120) transpose wo -> woT (1024x1024).
// ---------------------------------------------------------------------------
__device__ __forceinline__ void transpose_tile(
    const float* __restrict__ src, ushort* __restrict__ dst,
    int R, int Ncols, int r0, int c0, float (*t)[65], int tid) {
  const int lr = tid >> 2;
  const int lc = (tid & 3) * 16;
  const float* sp = src + (size_t)(r0 + lr) * Ncols + c0 + lc;
  #pragma unroll
  for (int j = 0; j < 4; ++j) {
    float4 v = *(const float4*)(sp + j * 4);
    t[lr][lc + j * 4 + 0] = v.x;
    t[lr][lc + j * 4 + 1] = v.y;
    t[lr][lc + j * 4 + 2] = v.z;
    t[lr][lc + j * 4 + 3] = v.w;
  }
  __syncthreads();
  ushort out[16];
  #pragma unroll
  for (int j = 0; j < 16; ++j)
    out[j] = f2bf(t[lc + j][lr]);
  ushort* dp = dst + (size_t)(c0 + lr) * R + r0 + lc;
  *(uint4*)dp = *(const uint4*)&out[0];
  *(uint4*)(dp + 8) = *(const uint4*)&out[8];
}

__global__ __launch_bounds__(256) void prep(
    const float* __restrict__ x, const float* __restrict__ wqkv,
    const float* __restrict__ wo, ushort* __restrict__ xb,
    ushort* __restrict__ wqkvT, ushort* __restrict__ woT) {
  __shared__ float t[64][65];
  const int bid = blockIdx.x;
  const int tid = threadIdx.x;
  if (bid < 4096) {
    const int i = bid * 256 + tid;
    float4 v = *(const float4*)(x + (size_t)i * 4);
    ushort4 o;
    o.x = f2bf(v.x); o.y = f2bf(v.y); o.z = f2bf(v.z); o.w = f2bf(v.w);
    *(ushort4*)(xb + (size_t)i * 4) = o;
  } else if (bid < 4096 + 768) {
    const int b2 = bid - 4096;             // wqkv: 1024 x 3072 -> 48 x 16 tiles
    const int bx = b2 % 48, by = b2 / 48;
    transpose_tile(wqkv, wqkvT, DMODEL, 3 * DMODEL, by * 64, bx * 64, t, tid);
  } else {
    const int b3 = bid - 4096 - 768;       // wo: 1024 x 1024 -> 16 x 16 tiles
    const int bx = b3 % 16, by = b3 / 16;
    transpose_tile(wo, woT, DMODEL, DMODEL, by * 64, bx * 64, t, tid);
  }
}

// ---------------------------------------------------------------------------
// GEMM1: 128x128 2-phase swizzled, bf16 out with LDS repack epilogue
// (merged LDS buffer required for the 34.8 KB repack region).
// Measured 44.8 us @ M=4096,N=3072,K=1024 (round 11).
// ---------------------------------------------------------------------------
__global__ __launch_bounds__(256) void gemm_b16(
    const ushort* __restrict__ A, const ushort* __restrict__ Bt,
    ushort* __restrict__ C, int M, int N, int K, int relu_limit) {
  __shared__ ushort sh[128 * CLP];     // K-loop carves A/B tiles; epilogue reuses
  ushort* Asm = sh;                    // [128*64]
  ushort* Bsm = sh + 128 * 64;         // [128*64]

  const int tid  = threadIdx.x;
  const int lane = tid & 63;
  const int w    = tid >> 6;
  const int wr   = w >> 1, wc = w & 1;
  const int brow = blockIdx.y * 128;
  const int bcol = blockIdx.x * 128;

  f32x4 acc[4][4];
  #pragma unroll
  for (int i = 0; i < 4; ++i)
    #pragma unroll
    for (int j = 0; j < 4; ++j) acc[i][j] = (f32x4)0.f;

  const int r8   = lane >> 3;
  const int arow = w * 32 + r8;
  const int acol = ((lane & 7) ^ r8) * 8;   // pre-swizzled global source col
  const ushort* Ag = A  + (size_t)(brow + arow) * K + acol;
  const ushort* Bg = Bt + (size_t)(bcol + arow) * K + acol;

  const int l15 = lane & 15;
  const int khi = (lane >> 4) * 8;

  for (int k0 = 0; k0 < K; k0 += 64) {
    #pragma unroll
    for (int u = 0; u < 4; ++u) {
      gload_lds16(Ag + k0 + (size_t)u * 8 * K, &Asm[(w * 4 + u) * 512]);
      gload_lds16(Bg + k0 + (size_t)u * 8 * K, &Bsm[(w * 4 + u) * 512]);
    }
    __syncthreads();
    #pragma unroll
    for (int kk = 0; kk < 2; ++kk) {
      const int ko = kk * 32 + khi;
      bf16x8 af[4], bfr[4];
      #pragma unroll
      for (int mi = 0; mi < 4; ++mi) {
        const int row = wr * 64 + mi * 16 + l15;
        af[mi] = *(const bf16x8*)&Asm[row * 64 + (ko ^ ((row & 7) << 3))];
      }
      #pragma unroll
      for (int ni = 0; ni < 4; ++ni) {
        const int row = wc * 64 + ni * 16 + l15;
        bfr[ni] = *(const bf16x8*)&Bsm[row * 64 + (ko ^ ((row & 7) << 3))];
      }
      #pragma unroll
      for (int mi = 0; mi < 4; ++mi)
        #pragma unroll
        for (int ni = 0; ni < 4; ++ni)
          acc[mi][ni] = __builtin_amdgcn_mfma_f32_16x16x32_bf16(
              af[mi], bfr[ni], acc[mi][ni], 0, 0, 0);
    }
    __syncthreads();
  }

  // ---- repack through LDS, then coalesced dwordx4 row stores ----
  #pragma unroll
  for (int mi = 0; mi < 4; ++mi) {
    #pragma unroll
    for (int ni = 0; ni < 4; ++ni) {
      const int row0 = wr * 64 + mi * 16 + (lane >> 4) * 4;
      const int col  = wc * 64 + ni * 16 + l15;
      const bool rl  = bcol + col < relu_limit;
      #pragma unroll
      for (int i = 0; i < 4; ++i) {
        float v = acc[mi][ni][i];
        if (rl) v = fmaxf(v, 0.f);
        sh[(row0 + i) * CLP + col] = f2bf(v);
      }
    }
  }
  __syncthreads();
  const int r    = tid >> 1;
  const int cseg = (tid & 1) * 64;
  ushort* dst = C + (size_t)(brow + r) * N + bcol + cseg;
  const ushort* srcp = &sh[r * CLP + cseg];
  #pragma unroll
  for (int j = 0; j < 8; ++j)
    *(ushort8*)(dst + j * 8) = *(const ushort8*)(srcp + j * 8);
}

// ---------------------------------------------------------------------------
// GEMM2: 128x128 2-phase swizzled, f32 out, SEPARATE static LDS arrays
// (round-9 exact structure — merged-buffer variant regressed ~60%).
// ---------------------------------------------------------------------------
__global__ __launch_bounds__(256) void gemm_f32(
    const ushort* __restrict__ A, const ushort* __restrict__ Bt,
    float* __restrict__ C, int M, int N, int K, int relu_limit) {
  __shared__ ushort Asm[128 * 64];
  __shared__ ushort Bsm[128 * 64];

  const int tid  = threadIdx.x;
  const int lane = tid & 63;
  const int w    = tid >> 6;
  const int wr   = w >> 1, wc = w & 1;
  const int brow = blockIdx.y * 128;
  const int bcol = blockIdx.x * 128;

  f32x4 acc[4][4];
  #pragma unroll
  for (int i = 0; i < 4; ++i)
    #pragma unroll
    for (int j = 0; j < 4; ++j) acc[i][j] = (f32x4)0.f;

  const int r8   = lane >> 3;
  const int arow = w * 32 + r8;
  const int acol = ((lane & 7) ^ r8) * 8;
  const ushort* Ag = A  + (size_t)(brow + arow) * K + acol;
  const ushort* Bg = Bt + (size_t)(bcol + arow) * K + acol;

  const int l15 = lane & 15;
  const int khi = (lane >> 4) * 8;

  for (int k0 = 0; k0 < K; k0 += 64) {
    #pragma unroll
    for (int u = 0; u < 4; ++u) {
      gload_lds16(Ag + k0 + (size_t)u * 8 * K, &Asm[(w * 4 + u) * 512]);
      gload_lds16(Bg + k0 + (size_t)u * 8 * K, &Bsm[(w * 4 + u) * 512]);
    }
    __syncthreads();
    #pragma unroll
    for (int kk = 0; kk < 2; ++kk) {
      const int ko = kk * 32 + khi;
      bf16x8 af[4], bfr[4];
      #pragma unroll
      for (int mi = 0; mi < 4; ++mi) {
        const int row = wr * 64 + mi * 16 + l15;
        af[mi] = *(const bf16x8*)&Asm[row * 64 + (ko ^ ((row & 7) << 3))];
      }
      #pragma unroll
      for (int ni = 0; ni < 4; ++ni) {
        const int row = wc * 64 + ni * 16 + l15;
        bfr[ni] = *(const bf16x8*)&Bsm[row * 64 + (ko ^ ((row & 7) << 3))];
      }
      #pragma unroll
      for (int mi = 0; mi < 4; ++mi)
        #pragma unroll
        for (int ni = 0; ni < 4; ++ni)
          acc[mi][ni] = __builtin_amdgcn_mfma_f32_16x16x32_bf16(
              af[mi], bfr[ni], acc[mi][ni], 0, 0, 0);
    }
    __syncthreads();
  }

  #pragma unroll
  for (int mi = 0; mi < 4; ++mi) {
    #pragma unroll
    for (int ni = 0; ni < 4; ++ni) {
      const int r0  = brow + wr * 64 + mi * 16 + (lane >> 4) * 4;
      const int col = bcol + wc * 64 + ni * 16 + l15;
      const bool rl = col < relu_limit;
      #pragma unroll
      for (int i = 0; i < 4; ++i) {
        float v = acc[mi][ni][i];
        if (rl) v = fmaxf(v, 0.f);
        C[(size_t)(r0 + i) * N + col] = v;
      }
    }
  }
}

// ---------------------------------------------------------------------------
// Kernel A (MFMA): state[bh,c] = { KVT[e][d] = sum_t V[t][e] K[t][d], ksum[d] }
// state bf16.
// ---------------------------------------------------------------------------
__global__ __launch_bounds__(256) void chunk_sums_mfma(
    const ushort* __restrict__ qkvb, ushort* __restrict__ state) {
  __shared__ ushort Kt[64 * LP];   // Kt[d][t]
  __shared__ ushort Vt[64 * LP];   // Vt[e][t]

  const int bh = blockIdx.x >> 5;
  const int c  = blockIdx.x & (NC - 1);
  const int b  = bh >> 4;
  const int h  = bh & (NHEADS - 1);
  const int tid = threadIdx.x;

  const size_t rs   = 3 * DMODEL;
  const size_t base = ((size_t)(b * SEQ + c * CS)) * rs + (size_t)h * HD;

  const int r  = tid >> 2;          // timestep row 0..63
  const int sg = (tid & 3) * 16;    // col segment
  {
    const ushort* src = qkvb + base + (size_t)r * rs + sg;
    ushort8 k0 = *(const ushort8*)(src + DMODEL);
    ushort8 k1 = *(const ushort8*)(src + DMODEL + 8);
    ushort8 v0 = *(const ushort8*)(src + 2 * DMODEL);
    ushort8 v1 = *(const ushort8*)(src + 2 * DMODEL + 8);
    #pragma unroll
    for (int j = 0; j < 8; ++j) {
      Kt[(sg + j) * LP + r]     = k0[j];
      Kt[(sg + 8 + j) * LP + r] = k1[j];
      Vt[(sg + j) * LP + r]     = v0[j];
      Vt[(sg + 8 + j) * LP + r] = v1[j];
    }
  }
  __syncthreads();

  const int lane = tid & 63;
  const int w    = tid >> 6;
  const int l15  = lane & 15;
  const int khi  = (lane >> 4) * 8;

  bf16x8 va[2];
  #pragma unroll
  for (int kk = 0; kk < 2; ++kk)
    va[kk] = *(const bf16x8*)&Vt[(w * 16 + l15) * LP + kk * 32 + khi];

  f32x4 a[4];
  #pragma unroll
  for (int ct = 0; ct < 4; ++ct) {
    a[ct] = (f32x4)0.f;
    #pragma unroll
    for (int kk = 0; kk < 2; ++kk)
      a[ct] = __builtin_amdgcn_mfma_f32_16x16x32_bf16(
          va[kk], *(const bf16x8*)&Kt[(ct * 16 + l15) * LP + kk * 32 + khi],
          a[ct], 0, 0, 0);
  }

  ushort* st = state + (size_t)blockIdx.x * STSZ;
  #pragma unroll
  for (int ct = 0; ct < 4; ++ct) {
    #pragma unroll
    for (int i = 0; i < 4; ++i) {
      const int e = w * 16 + (lane >> 4) * 4 + i;
      const int d = ct * 16 + l15;
      st[e * HD + d] = f2bf(a[ct][i]);
    }
  }

  if (tid < HD) {
    float s = 0.f;
    #pragma unroll 8
    for (int t = 0; t < CS; ++t) s += bf2f(Kt[tid * LP + t]);
    st[HD * HD + tid] = f2bf(s);
  }
}

// ---------------------------------------------------------------------------
// Kernel B: exclusive prefix over chunks, element-parallel. bf16 in/out,
// f32 running accumulator.
// ---------------------------------------------------------------------------
__global__ __launch_bounds__(256) void chunk_prefix(ushort* __restrict__ state) {
  const int g = blockIdx.x * 256 + threadIdx.x;
  const int total = 2 * NHEADS * STSZ;
  if (g >= total) return;
  const int bh   = g / STSZ;
  const int elem = g - bh * STSZ;
  ushort* p = state + (size_t)bh * NC * STSZ + elem;

  float run = 0.f;
  #pragma unroll
  for (int c = 0; c < NC; ++c) {
    const float t = bf2f(p[(size_t)c * STSZ]);
    p[(size_t)c * STSZ] = f2bf(run);
    run += t;
  }
}

// ---------------------------------------------------------------------------
// Kernel C (MFMA): per-(b,h,chunk) output, writes y bf16. state bf16.
// ---------------------------------------------------------------------------
__global__ __launch_bounds__(256) void chunk_out_mfma(
    const ushort* __restrict__ qkvb, const ushort* __restrict__ state,
    ushort* __restrict__ y) {
  __shared__ ushort Qs[64 * LP];   // Q[t][d]
  __shared__ ushort Ks[64 * LP];   // K[s][d]
  __shared__ ushort Vt[80 * LP];   // Vaug^T[n][s]: n<64 = V[s][n], n=64: ones
  __shared__ ushort Kv[80 * LP];   // KvAug^T[n][d]: n<64 = KVp[d][n], n=64: ksum
  __shared__ ushort Sm[64 * LP];   // masked S[t][s] bf16

  const int bh = blockIdx.x >> 5;
  const int c  = blockIdx.x & (NC - 1);
  const int b  = bh >> 4;
  const int h  = bh & (NHEADS - 1);
  const int tid = threadIdx.x;

  const size_t rs   = 3 * DMODEL;
  const size_t base = ((size_t)(b * SEQ + c * CS)) * rs + (size_t)h * HD;

  {
    const int r  = tid >> 2;
    const int sg = (tid & 3) * 16;
    const ushort* src = qkvb + base + (size_t)r * rs + sg;
    ushort8 q0 = *(const ushort8*)(src);
    ushort8 q1 = *(const ushort8*)(src + 8);
    ushort8 k0 = *(const ushort8*)(src + DMODEL);
    ushort8 k1 = *(const ushort8*)(src + DMODEL + 8);
    ushort8 v0 = *(const ushort8*)(src + 2 * DMODEL);
    ushort8 v1 = *(const ushort8*)(src + 2 * DMODEL + 8);
    *(ushort8*)&Qs[r * LP + sg]     = q0;
    *(ushort8*)&Qs[r * LP + sg + 8] = q1;
    *(ushort8*)&Ks[r * LP + sg]     = k0;
    *(ushort8*)&Ks[r * LP + sg + 8] = k1;
    #pragma unroll
    for (int j = 0; j < 8; ++j) {
      Vt[(sg + j) * LP + r]     = v0[j];
      Vt[(sg + 8 + j) * LP + r] = v1[j];
    }
  }
  // Vt rows 64..79: row 64 = 1.0, rest 0
  {
    const int idx = tid * 4;                 // 0..1023
    const int row = 64 + (idx >> 6);
    const int col = idx & 63;
    const ushort val = (row == 64) ? (ushort)0x3F80 : (ushort)0;
    ushort4 v4 = {val, val, val, val};
    *(ushort4*)&Vt[row * LP + col] = v4;
  }
  // Kv rows 0..63 direct bf16 copy; row 64 = ksum; rows 65..79 = 0
  {
    const ushort* sp = state + ((size_t)bh * NC + c) * STSZ;
    const int off = tid * 16;                // 0..4095
    const int e   = off >> 6;
    const int col = off & 63;
    *(ushort8*)&Kv[e * LP + col]     = *(const ushort8*)(sp + off);
    *(ushort8*)&Kv[e * LP + col + 8] = *(const ushort8*)(sp + off + 8);
    if (tid < 16) {
      const int c4 = tid * 4;
      *(ushort4*)&Kv[64 * LP + c4] = *(const ushort4*)(sp + HD * HD + c4);
    }
    if (tid < 240) {
      const int idx = tid * 4;               // 0..959
      const int row = 65 + (idx >> 6);
      const int col2 = idx & 63;
      ushort4 z = {0, 0, 0, 0};
      *(ushort4*)&Kv[row * LP + col2] = z;
    }
  }
  __syncthreads();

  const int lane = tid & 63;
  const int w    = tid >> 6;
  const int l15  = lane & 15;
  const int khi  = (lane >> 4) * 8;

  // ---- S = Q K^T for row stripe w*16..w*16+15 ----
  bf16x8 qa[2];
  #pragma unroll
  for (int kk = 0; kk < 2; ++kk)
    qa[kk] = *(const bf16x8*)&Qs[(w * 16 + l15) * LP + kk * 32 + khi];

  {
    f32x4 sac[4];
    #pragma unroll
    for (int ct = 0; ct < 4; ++ct) {
      sac[ct] = (f32x4)0.f;
      #pragma unroll
      for (int kk = 0; kk < 2; ++kk)
        sac[ct] = __builtin_amdgcn_mfma_f32_16x16x32_bf16(
            qa[kk], *(const bf16x8*)&Ks[(ct * 16 + l15) * LP + kk * 32 + khi],
            sac[ct], 0, 0, 0);
    }
    const int t0 = w * 16 + (lane >> 4) * 4;
    #pragma unroll
    for (int ct = 0; ct < 4; ++ct) {
      const int s = ct * 16 + l15;
      #pragma unroll
      for (int i = 0; i < 4; ++i) {
        const int t = t0 + i;
        const float v = (s <= t) ? sac[ct][i] : 0.f;
        Sm[t * LP + s] = f2bf(v);
      }
    }
  }
  __syncthreads();

  // ---- O = Q @ KvAug + Sm @ VtAug  (N = 80) ----
  bf16x8 sa[2];
  #pragma unroll
  for (int kk = 0; kk < 2; ++kk)
    sa[kk] = *(const bf16x8*)&Sm[(w * 16 + l15) * LP + kk * 32 + khi];

  f32x4 o[5];
  #pragma unroll
  for (int ct = 0; ct < 5; ++ct) {
    o[ct] = (f32x4)0.f;
    #pragma unroll
    for (int kk = 0; kk < 2; ++kk)
      o[ct] = __builtin_amdgcn_mfma_f32_16x16x32_bf16(
          qa[kk], *(const bf16x8*)&Kv[(ct * 16 + l15) * LP + kk * 32 + khi],
          o[ct], 0, 0, 0);
    #pragma unroll
    for (int kk = 0; kk < 2; ++kk)
      o[ct] = __builtin_amdgcn_mfma_f32_16x16x32_bf16(
          sa[kk], *(const bf16x8*)&Vt[(ct * 16 + l15) * LP + kk * 32 + khi],
          o[ct], 0, 0, 0);
  }

  // ---- epilogue: den broadcast within 16-lane group, write y ----
  float den[4];
  #pragma unroll
  for (int i = 0; i < 4; ++i)
    den[i] = __shfl(o[4][i], lane & 48) + EPS_LA;

  const int t0 = w * 16 + (lane >> 4) * 4;
  #pragma unroll
  for (int ct = 0; ct < 4; ++ct) {
    const int e = ct * 16 + l15;
    #pragma unroll
    for (int i = 0; i < 4; ++i) {
      const int t = t0 + i;
      y[((size_t)(b * SEQ + c * CS + t)) * DMODEL + (size_t)h * HD + e] =
          f2bf(o[ct][i] / den[i]);
    }
  }
}

// ---------------------------------------------------------------------------
extern "C" void kernel_launch(void* const* d_in, const int* in_sizes, int n_in,
                              void* d_out, int out_size, void* d_ws,
                              size_t ws_size, hipStream_t stream) {
  (void)in_sizes; (void)n_in; (void)out_size; (void)ws_size;
  const float* x    = (const float*)d_in[0];
  const float* wqkv = (const float*)d_in[1];
  const float* wo   = (const float*)d_in[2];
  float* out = (float*)d_out;

  const int M  = 2 * SEQ;     // 4096
  const int K  = DMODEL;      // 1024
  const int N1 = 3 * DMODEL;  // 3072
  const int N2 = DMODEL;      // 1024

  // workspace layout (~56 MiB)
  ushort* stateb = (ushort*)d_ws;                           // 8.125 MiB
  ushort* qkvb   = stateb + (size_t)2 * NHEADS * NC * STSZ; // 24 MiB
  ushort* xb     = qkvb + (size_t)M * N1;                   // 8 MiB
  ushort* yb     = xb + (size_t)M * K;                      // 8 MiB
  ushort* wqkvT  = yb + (size_t)M * K;                      // 6 MiB
  ushort* woT    = wqkvT + (size_t)K * N1;                  // 2 MiB

  dim3 blk(256);

  prep<<<dim3(4096 + 768 + 256), blk, 0, stream>>>(x, wqkv, wo, xb, wqkvT, woT);

  gemm_b16<<<dim3(N1 / 128, M / 128), blk, 0, stream>>>(
      xb, wqkvT, qkvb, M, N1, K, 2 * DMODEL);

  chunk_sums_mfma<<<dim3(2 * NHEADS * NC), blk, 0, stream>>>(qkvb, stateb);

  const int total = 2 * NHEADS * STSZ;
  chunk_prefix<<<dim3((total + 255) / 256), blk, 0, stream>>>(stateb);

  chunk_out_mfma<<<dim3(2 * NHEADS * NC), blk, 0, stream>>>(qkvb, stateb, yb);

  gemm_f32<<<dim3(N2 / 128, M / 128), blk, 0, stream>>>(
      yb, woT, out, M, N2, K, 0);
}

// Round 13
// 92.802 us; speedup vs baseline: 1.0290x; 1.0290x over previous
//
#include <hip/hip_runtime.h>
#include <hip/hip_bf16.h>

#define SEQ    2048
#define DMODEL 1024
#define NHEADS 16
#define HD     64
#define CS     64
#define NC     (SEQ / CS)
#define STSZ   (HD * HD + HD)   // 4160 bf16: KVT[64][64] + ksum[64]
#define EPS_LA 1e-5f
#define LP     72               // padded LDS row stride (bf16 elems)

typedef __attribute__((ext_vector_type(8))) short  bf16x8;
typedef __attribute__((ext_vector_type(8))) unsigned short ushort8;
typedef __attribute__((ext_vector_type(4))) float  f32x4;

__device__ __forceinline__ void gload_lds16(const void* g, void* l) {
  __builtin_amdgcn_global_load_lds(
      (const __attribute__((address_space(1))) void*)g,
      (__attribute__((address_space(3))) void*)l, 16, 0, 0);
}

__device__ __forceinline__ ushort f2bf(float x) {
  __hip_bfloat16 h = __float2bfloat16(x);
  return __builtin_bit_cast(ushort, h);
}
__device__ __forceinline__ float bf2f(ushort u) {
  unsigned int v = ((unsigned int)u) << 16;
  return __builtin_bit_cast(float, v);
}

// ---------------------------------------------------------------------------
// prep (weights only): blocks [0,768) transpose wqkv -> wqkvT (3072x1024);
// [768,1024) transpose wo -> woT (1024x1024). x is consumed as f32 by GEMM1.
// ---------------------------------------------------------------------------
__device__ __forceinline__ void transpose_tile(
    const float* __restrict__ src, ushort* __restrict__ dst,
    int R, int Ncols, int r0, int c0, float (*t)[65], int tid) {
  const int lr = tid >> 2;
  const int lc = (tid & 3) * 16;
  const float* sp = src + (size_t)(r0 + lr) * Ncols + c0 + lc;
  #pragma unroll
  for (int j = 0; j < 4; ++j) {
    float4 v = *(const float4*)(sp + j * 4);
    t[lr][lc + j * 4 + 0] = v.x;
    t[lr][lc + j * 4 + 1] = v.y;
    t[lr][lc + j * 4 + 2] = v.z;
    t[lr][lc + j * 4 + 3] = v.w;
  }
  __syncthreads();
  ushort out[16];
  #pragma unroll
  for (int j = 0; j < 16; ++j)
    out[j] = f2bf(t[lc + j][lr]);
  ushort* dp = dst + (size_t)(c0 + lr) * R + r0 + lc;
  *(uint4*)dp = *(const uint4*)&out[0];
  *(uint4*)(dp + 8) = *(const uint4*)&out[8];
}

__global__ __launch_bounds__(256) void prep(
    const float* __restrict__ wqkv, const float* __restrict__ wo,
    ushort* __restrict__ wqkvT, ushort* __restrict__ woT) {
  __shared__ float t[64][65];
  const int bid = blockIdx.x;
  const int tid = threadIdx.x;
  if (bid < 768) {
    const int bx = bid % 48, by = bid / 48;   // wqkv: 1024 x 3072
    transpose_tile(wqkv, wqkvT, DMODEL, 3 * DMODEL, by * 64, bx * 64, t, tid);
  } else {
    const int b3 = bid - 768;                 // wo: 1024 x 1024
    const int bx = b3 % 16, by = b3 / 16;
    transpose_tile(wo, woT, DMODEL, DMODEL, by * 64, bx * 64, t, tid);
  }
}

// ---------------------------------------------------------------------------
// GEMM1: C(bf16) = relu-part( X(f32, MxK) * wqkvT(NxK)^T ). A-path reads X
// as f32 and converts to bf16 during reg-staged LDS writes (fuses the old
// conv_bf16 pass). B-path via global_load_lds. Round-9 proven K-loop:
// separate static LDS arrays, XOR swizzle both sides, scattered bf16 stores.
// ---------------------------------------------------------------------------
__global__ __launch_bounds__(256) void gemm_x_b16(
    const float* __restrict__ Xf, const ushort* __restrict__ Bt,
    ushort* __restrict__ C, int M, int N, int K, int relu_limit) {
  __shared__ ushort Asm[128 * 64];
  __shared__ ushort Bsm[128 * 64];

  const int tid  = threadIdx.x;
  const int lane = tid & 63;
  const int w    = tid >> 6;
  const int wr   = w >> 1, wc = w & 1;
  const int brow = blockIdx.y * 128;
  const int bcol = blockIdx.x * 128;

  f32x4 acc[4][4];
  #pragma unroll
  for (int i = 0; i < 4; ++i)
    #pragma unroll
    for (int j = 0; j < 4; ++j) acc[i][j] = (f32x4)0.f;

  const int r8   = lane >> 3;
  const int arow = w * 32 + r8;                // + u*8
  const int acol = ((lane & 7) ^ r8) * 8;      // pre-swizzled source col
  const float*  Ag = Xf + (size_t)(brow + arow) * K + acol;
  const ushort* Bg = Bt + (size_t)(bcol + arow) * K + acol;

  const int l15 = lane & 15;
  const int khi = (lane >> 4) * 8;

  for (int k0 = 0; k0 < K; k0 += 64) {
    // B: async global->LDS
    #pragma unroll
    for (int u = 0; u < 4; ++u)
      gload_lds16(Bg + k0 + (size_t)u * 8 * K, &Bsm[(w * 4 + u) * 512]);
    // A: f32 load -> cvt -> ds_write_b128 (same linear layout as gload)
    #pragma unroll
    for (int u = 0; u < 4; ++u) {
      const float* src = Ag + k0 + (size_t)u * 8 * K;
      float4 f0 = *(const float4*)src;
      float4 f1 = *(const float4*)(src + 4);
      ushort8 p;
      p[0] = f2bf(f0.x); p[1] = f2bf(f0.y); p[2] = f2bf(f0.z); p[3] = f2bf(f0.w);
      p[4] = f2bf(f1.x); p[5] = f2bf(f1.y); p[6] = f2bf(f1.z); p[7] = f2bf(f1.w);
      *(ushort8*)&Asm[(w * 4 + u) * 512 + lane * 8] = p;
    }
    __syncthreads();
    #pragma unroll
    for (int kk = 0; kk < 2; ++kk) {
      const int ko = kk * 32 + khi;
      bf16x8 af[4], bfr[4];
      #pragma unroll
      for (int mi = 0; mi < 4; ++mi) {
        const int row = wr * 64 + mi * 16 + l15;
        af[mi] = *(const bf16x8*)&Asm[row * 64 + (ko ^ ((row & 7) << 3))];
      }
      #pragma unroll
      for (int ni = 0; ni < 4; ++ni) {
        const int row = wc * 64 + ni * 16 + l15;
        bfr[ni] = *(const bf16x8*)&Bsm[row * 64 + (ko ^ ((row & 7) << 3))];
      }
      #pragma unroll
      for (int mi = 0; mi < 4; ++mi)
        #pragma unroll
        for (int ni = 0; ni < 4; ++ni)
          acc[mi][ni] = __builtin_amdgcn_mfma_f32_16x16x32_bf16(
              af[mi], bfr[ni], acc[mi][ni], 0, 0, 0);
    }
    __syncthreads();
  }

  #pragma unroll
  for (int mi = 0; mi < 4; ++mi) {
    #pragma unroll
    for (int ni = 0; ni < 4; ++ni) {
      const int r0  = brow + wr * 64 + mi * 16 + (lane >> 4) * 4;
      const int col = bcol + wc * 64 + ni * 16 + l15;
      const bool rl = col < relu_limit;
      #pragma unroll
      for (int i = 0; i < 4; ++i) {
        float v = acc[mi][ni][i];
        if (rl) v = fmaxf(v, 0.f);
        C[(size_t)(r0 + i) * N + col] = f2bf(v);
      }
    }
  }
}

// ---------------------------------------------------------------------------
// GEMM2: 128x128 2-phase swizzled, bf16 in, f32 out (round-9 exact).
// ---------------------------------------------------------------------------
__global__ __launch_bounds__(256) void gemm_f32(
    const ushort* __restrict__ A, const ushort* __restrict__ Bt,
    float* __restrict__ C, int M, int N, int K, int relu_limit) {
  __shared__ ushort Asm[128 * 64];
  __shared__ ushort Bsm[128 * 64];

  const int tid  = threadIdx.x;
  const int lane = tid & 63;
  const int w    = tid >> 6;
  const int wr   = w >> 1, wc = w & 1;
  const int brow = blockIdx.y * 128;
  const int bcol = blockIdx.x * 128;

  f32x4 acc[4][4];
  #pragma unroll
  for (int i = 0; i < 4; ++i)
    #pragma unroll
    for (int j = 0; j < 4; ++j) acc[i][j] = (f32x4)0.f;

  const int r8   = lane >> 3;
  const int arow = w * 32 + r8;
  const int acol = ((lane & 7) ^ r8) * 8;
  const ushort* Ag = A  + (size_t)(brow + arow) * K + acol;
  const ushort* Bg = Bt + (size_t)(bcol + arow) * K + acol;

  const int l15 = lane & 15;
  const int khi = (lane >> 4) * 8;

  for (int k0 = 0; k0 < K; k0 += 64) {
    #pragma unroll
    for (int u = 0; u < 4; ++u) {
      gload_lds16(Ag + k0 + (size_t)u * 8 * K, &Asm[(w * 4 + u) * 512]);
      gload_lds16(Bg + k0 + (size_t)u * 8 * K, &Bsm[(w * 4 + u) * 512]);
    }
    __syncthreads();
    #pragma unroll
    for (int kk = 0; kk < 2; ++kk) {
      const int ko = kk * 32 + khi;
      bf16x8 af[4], bfr[4];
      #pragma unroll
      for (int mi = 0; mi < 4; ++mi) {
        const int row = wr * 64 + mi * 16 + l15;
        af[mi] = *(const bf16x8*)&Asm[row * 64 + (ko ^ ((row & 7) << 3))];
      }
      #pragma unroll
      for (int ni = 0; ni < 4; ++ni) {
        const int row = wc * 64 + ni * 16 + l15;
        bfr[ni] = *(const bf16x8*)&Bsm[row * 64 + (ko ^ ((row & 7) << 3))];
      }
      #pragma unroll
      for (int mi = 0; mi < 4; ++mi)
        #pragma unroll
        for (int ni = 0; ni < 4; ++ni)
          acc[mi][ni] = __builtin_amdgcn_mfma_f32_16x16x32_bf16(
              af[mi], bfr[ni], acc[mi][ni], 0, 0, 0);
    }
    __syncthreads();
  }

  #pragma unroll
  for (int mi = 0; mi < 4; ++mi) {
    #pragma unroll
    for (int ni = 0; ni < 4; ++ni) {
      const int r0  = brow + wr * 64 + mi * 16 + (lane >> 4) * 4;
      const int col = bcol + wc * 64 + ni * 16 + l15;
      const bool rl = col < relu_limit;
      #pragma unroll
      for (int i = 0; i < 4; ++i) {
        float v = acc[mi][ni][i];
        if (rl) v = fmaxf(v, 0.f);
        C[(size_t)(r0 + i) * N + col] = v;
      }
    }
  }
}

// ---------------------------------------------------------------------------
// Kernel A (MFMA): state[bh,c] = { KVT[e][d] = sum_t V[t][e] K[t][d], ksum[d] }
// state bf16.
// ---------------------------------------------------------------------------
__global__ __launch_bounds__(256) void chunk_sums_mfma(
    const ushort* __restrict__ qkvb, ushort* __restrict__ state) {
  __shared__ ushort Kt[64 * LP];   // Kt[d][t]
  __shared__ ushort Vt[64 * LP];   // Vt[e][t]

  const int bh = blockIdx.x >> 5;
  const int c  = blockIdx.x & (NC - 1);
  const int b  = bh >> 4;
  const int h  = bh & (NHEADS - 1);
  const int tid = threadIdx.x;

  const size_t rs   = 3 * DMODEL;
  const size_t base = ((size_t)(b * SEQ + c * CS)) * rs + (size_t)h * HD;

  const int r  = tid >> 2;          // timestep row 0..63
  const int sg = (tid & 3) * 16;    // col segment
  {
    const ushort* src = qkvb + base + (size_t)r * rs + sg;
    ushort8 k0 = *(const ushort8*)(src + DMODEL);
    ushort8 k1 = *(const ushort8*)(src + DMODEL + 8);
    ushort8 v0 = *(const ushort8*)(src + 2 * DMODEL);
    ushort8 v1 = *(const ushort8*)(src + 2 * DMODEL + 8);
    #pragma unroll
    for (int j = 0; j < 8; ++j) {
      Kt[(sg + j) * LP + r]     = k0[j];
      Kt[(sg + 8 + j) * LP + r] = k1[j];
      Vt[(sg + j) * LP + r]     = v0[j];
      Vt[(sg + 8 + j) * LP + r] = v1[j];
    }
  }
  __syncthreads();

  const int lane = tid & 63;
  const int w    = tid >> 6;
  const int l15  = lane & 15;
  const int khi  = (lane >> 4) * 8;

  bf16x8 va[2];
  #pragma unroll
  for (int kk = 0; kk < 2; ++kk)
    va[kk] = *(const bf16x8*)&Vt[(w * 16 + l15) * LP + kk * 32 + khi];

  f32x4 a[4];
  #pragma unroll
  for (int ct = 0; ct < 4; ++ct) {
    a[ct] = (f32x4)0.f;
    #pragma unroll
    for (int kk = 0; kk < 2; ++kk)
      a[ct] = __builtin_amdgcn_mfma_f32_16x16x32_bf16(
          va[kk], *(const bf16x8*)&Kt[(ct * 16 + l15) * LP + kk * 32 + khi],
          a[ct], 0, 0, 0);
  }

  ushort* st = state + (size_t)blockIdx.x * STSZ;
  #pragma unroll
  for (int ct = 0; ct < 4; ++ct) {
    #pragma unroll
    for (int i = 0; i < 4; ++i) {
      const int e = w * 16 + (lane >> 4) * 4 + i;
      const int d = ct * 16 + l15;
      st[e * HD + d] = f2bf(a[ct][i]);
    }
  }

  if (tid < HD) {
    float s = 0.f;
    #pragma unroll 8
    for (int t = 0; t < CS; ++t) s += bf2f(Kt[tid * LP + t]);
    st[HD * HD + tid] = f2bf(s);
  }
}

// ---------------------------------------------------------------------------
// Kernel B: exclusive prefix over chunks, element-parallel. bf16 in/out,
// f32 running accumulator.
// ---------------------------------------------------------------------------
__global__ __launch_bounds__(256) void chunk_prefix(ushort* __restrict__ state) {
  const int g = blockIdx.x * 256 + threadIdx.x;
  const int total = 2 * NHEADS * STSZ;
  if (g >= total) return;
  const int bh   = g / STSZ;
  const int elem = g - bh * STSZ;
  ushort* p = state + (size_t)bh * NC * STSZ + elem;

  float run = 0.f;
  #pragma unroll
  for (int c = 0; c < NC; ++c) {
    const float t = bf2f(p[(size_t)c * STSZ]);
    p[(size_t)c * STSZ] = f2bf(run);
    run += t;
  }
}

// ---------------------------------------------------------------------------
// Kernel C (MFMA): per-(b,h,chunk) output, writes y bf16. state bf16.
// ---------------------------------------------------------------------------
__global__ __launch_bounds__(256) void chunk_out_mfma(
    const ushort* __restrict__ qkvb, const ushort* __restrict__ state,
    ushort* __restrict__ y) {
  __shared__ ushort Qs[64 * LP];   // Q[t][d]
  __shared__ ushort Ks[64 * LP];   // K[s][d]
  __shared__ ushort Vt[80 * LP];   // Vaug^T[n][s]: n<64 = V[s][n], n=64: ones
  __shared__ ushort Kv[80 * LP];   // KvAug^T[n][d]: n<64 = KVp[d][n], n=64: ksum
  __shared__ ushort Sm[64 * LP];   // masked S[t][s] bf16

  const int bh = blockIdx.x >> 5;
  const int c  = blockIdx.x & (NC - 1);
  const int b  = bh >> 4;
  const int h  = bh & (NHEADS - 1);
  const int tid = threadIdx.x;

  const size_t rs   = 3 * DMODEL;
  const size_t base = ((size_t)(b * SEQ + c * CS)) * rs + (size_t)h * HD;

  {
    const int r  = tid >> 2;
    const int sg = (tid & 3) * 16;
    const ushort* src = qkvb + base + (size_t)r * rs + sg;
    ushort8 q0 = *(const ushort8*)(src);
    ushort8 q1 = *(const ushort8*)(src + 8);
    ushort8 k0 = *(const ushort8*)(src + DMODEL);
    ushort8 k1 = *(const ushort8*)(src + DMODEL + 8);
    ushort8 v0 = *(const ushort8*)(src + 2 * DMODEL);
    ushort8 v1 = *(const ushort8*)(src + 2 * DMODEL + 8);
    *(ushort8*)&Qs[r * LP + sg]     = q0;
    *(ushort8*)&Qs[r * LP + sg + 8] = q1;
    *(ushort8*)&Ks[r * LP + sg]     = k0;
    *(ushort8*)&Ks[r * LP + sg + 8] = k1;
    #pragma unroll
    for (int j = 0; j < 8; ++j) {
      Vt[(sg + j) * LP + r]     = v0[j];
      Vt[(sg + 8 + j) * LP + r] = v1[j];
    }
  }
  // Vt rows 64..79: row 64 = 1.0, rest 0
  {
    const int idx = tid * 4;                 // 0..1023
    const int row = 64 + (idx >> 6);
    const int col = idx & 63;
    const ushort val = (row == 64) ? (ushort)0x3F80 : (ushort)0;
    ushort4 v4 = {val, val, val, val};
    *(ushort4*)&Vt[row * LP + col] = v4;
  }
  // Kv rows 0..63 direct bf16 copy; row 64 = ksum; rows 65..79 = 0
  {
    const ushort* sp = state + ((size_t)bh * NC + c) * STSZ;
    const int off = tid * 16;                // 0..4095
    const int e   = off >> 6;
    const int col = off & 63;
    *(ushort8*)&Kv[e * LP + col]     = *(const ushort8*)(sp + off);
    *(ushort8*)&Kv[e * LP + col + 8] = *(const ushort8*)(sp + off + 8);
    if (tid < 16) {
      const int c4 = tid * 4;
      *(ushort4*)&Kv[64 * LP + c4] = *(const ushort4*)(sp + HD * HD + c4);
    }
    if (tid < 240) {
      const int idx = tid * 4;               // 0..959
      const int row = 65 + (idx >> 6);
      const int col2 = idx & 63;
      ushort4 z = {0, 0, 0, 0};
      *(ushort4*)&Kv[row * LP + col2] = z;
    }
  }
  __syncthreads();

  const int lane = tid & 63;
  const int w    = tid >> 6;
  const int l15  = lane & 15;
  const int khi  = (lane >> 4) * 8;

  // ---- S = Q K^T for row stripe w*16..w*16+15 ----
  bf16x8 qa[2];
  #pragma unroll
  for (int kk = 0; kk < 2; ++kk)
    qa[kk] = *(const bf16x8*)&Qs[(w * 16 + l15) * LP + kk * 32 + khi];

  {
    f32x4 sac[4];
    #pragma unroll
    for (int ct = 0; ct < 4; ++ct) {
      sac[ct] = (f32x4)0.f;
      #pragma unroll
      for (int kk = 0; kk < 2; ++kk)
        sac[ct] = __builtin_amdgcn_mfma_f32_16x16x32_bf16(
            qa[kk], *(const bf16x8*)&Ks[(ct * 16 + l15) * LP + kk * 32 + khi],
            sac[ct], 0, 0, 0);
    }
    const int t0 = w * 16 + (lane >> 4) * 4;
    #pragma unroll
    for (int ct = 0; ct < 4; ++ct) {
      const int s = ct * 16 + l15;
      #pragma unroll
      for (int i = 0; i < 4; ++i) {
        const int t = t0 + i;
        const float v = (s <= t) ? sac[ct][i] : 0.f;
        Sm[t * LP + s] = f2bf(v);
      }
    }
  }
  __syncthreads();

  // ---- O = Q @ KvAug + Sm @ VtAug  (N = 80) ----
  bf16x8 sa[2];
  #pragma unroll
  for (int kk = 0; kk < 2; ++kk)
    sa[kk] = *(const bf16x8*)&Sm[(w * 16 + l15) * LP + kk * 32 + khi];

  f32x4 o[5];
  #pragma unroll
  for (int ct = 0; ct < 5; ++ct) {
    o[ct] = (f32x4)0.f;
    #pragma unroll
    for (int kk = 0; kk < 2; ++kk)
      o[ct] = __builtin_amdgcn_mfma_f32_16x16x32_bf16(
          qa[kk], *(const bf16x8*)&Kv[(ct * 16 + l15) * LP + kk * 32 + khi],
          o[ct], 0, 0, 0);
    #pragma unroll
    for (int kk = 0; kk < 2; ++kk)
      o[ct] = __builtin_amdgcn_mfma_f32_16x16x32_bf16(
          sa[kk], *(const bf16x8*)&Vt[(ct * 16 + l15) * LP + kk * 32 + khi],
          o[ct], 0, 0, 0);
  }

  // ---- epilogue: den broadcast within 16-lane group, write y ----
  float den[4];
  #pragma unroll
  for (int i = 0; i < 4; ++i)
    den[i] = __shfl(o[4][i], lane & 48) + EPS_LA;

  const int t0 = w * 16 + (lane >> 4) * 4;
  #pragma unroll
  for (int ct = 0; ct < 4; ++ct) {
    const int e = ct * 16 + l15;
    #pragma unroll
    for (int i = 0; i < 4; ++i) {
      const int t = t0 + i;
      y[((size_t)(b * SEQ + c * CS + t)) * DMODEL + (size_t)h * HD + e] =
          f2bf(o[ct][i] / den[i]);
    }
  }
}

// ---------------------------------------------------------------------------
extern "C" void kernel_launch(void* const* d_in, const int* in_sizes, int n_in,
                              void* d_out, int out_size, void* d_ws,
                              size_t ws_size, hipStream_t stream) {
  (void)in_sizes; (void)n_in; (void)out_size; (void)ws_size;
  const float* x    = (const float*)d_in[0];
  const float* wqkv = (const float*)d_in[1];
  const float* wo   = (const float*)d_in[2];
  float* out = (float*)d_out;

  const int M  = 2 * SEQ;     // 4096
  const int K  = DMODEL;      // 1024
  const int N1 = 3 * DMODEL;  // 3072
  const int N2 = DMODEL;      // 1024

  // workspace layout (~48 MiB)
  ushort* stateb = (ushort*)d_ws;                           // 8.125 MiB
  ushort* qkvb   = stateb + (size_t)2 * NHEADS * NC * STSZ; // 24 MiB
  ushort* yb     = qkvb + (size_t)M * N1;                   // 8 MiB
  ushort* wqkvT  = yb + (size_t)M * K;                      // 6 MiB
  ushort* woT    = wqkvT + (size_t)K * N1;                  // 2 MiB

  dim3 blk(256);

  prep<<<dim3(768 + 256), blk, 0, stream>>>(wqkv, wo, wqkvT, woT);

  gemm_x_b16<<<dim3(N1 / 128, M / 128), blk, 0, stream>>>(
      x, wqkvT, qkvb, M, N1, K, 2 * DMODEL);

  chunk_sums_mfma<<<dim3(2 * NHEADS * NC), blk, 0, stream>>>(qkvb, stateb);

  const int total = 2 * NHEADS * STSZ;
  chunk_prefix<<<dim3((total + 255) / 256), blk, 0, stream>>>(stateb);

  chunk_out_mfma<<<dim3(2 * NHEADS * NC), blk, 0, stream>>>(qkvb, stateb, yb);

  gemm_f32<<<dim3(N2 / 128, M / 128), blk, 0, stream>>>(
      yb, woT, out, M, N2, K, 0);
}

// Round 14
// 90.082 us; speedup vs baseline: 1.0600x; 1.0302x over previous
//
#include <hip/hip_runtime.h>
#include <hip/hip_bf16.h>

#define SEQ    2048
#define DMODEL 1024
#define NHEADS 16
#define HD     64
#define CS     64
#define NC     (SEQ / CS)
#define STSZ   (HD * HD + HD)   // 4160 bf16: KVT[64][64] + ksum[64]
#define EPS_LA 1e-5f
#define LP     72               // padded LDS row stride (bf16 elems)

typedef __attribute__((ext_vector_type(8))) short  bf16x8;
typedef __attribute__((ext_vector_type(8))) unsigned short ushort8;
typedef __attribute__((ext_vector_type(4))) float  f32x4;

__device__ __forceinline__ void gload_lds16(const void* g, void* l) {
  __builtin_amdgcn_global_load_lds(
      (const __attribute__((address_space(1))) void*)g,
      (__attribute__((address_space(3))) void*)l, 16, 0, 0);
}

__device__ __forceinline__ ushort f2bf(float x) {
  __hip_bfloat16 h = __float2bfloat16(x);
  return __builtin_bit_cast(ushort, h);
}
__device__ __forceinline__ float bf2f(ushort u) {
  unsigned int v = ((unsigned int)u) << 16;
  return __builtin_bit_cast(float, v);
}

// ---------------------------------------------------------------------------
// Fused prep: blocks [0,4096) convert x f32->bf16; [4096,4864) transpose wqkv
// -> wqkvT (3072x1024); [4864,5120) transpose wo -> woT (1024x1024).
// ---------------------------------------------------------------------------
__device__ __forceinline__ void transpose_tile(
    const float* __restrict__ src, ushort* __restrict__ dst,
    int R, int Ncols, int r0, int c0, float (*t)[65], int tid) {
  const int lr = tid >> 2;
  const int lc = (tid & 3) * 16;
  const float* sp = src + (size_t)(r0 + lr) * Ncols + c0 + lc;
  #pragma unroll
  for (int j = 0; j < 4; ++j) {
    float4 v = *(const float4*)(sp + j * 4);
    t[lr][lc + j * 4 + 0] = v.x;
    t[lr][lc + j * 4 + 1] = v.y;
    t[lr][lc + j * 4 + 2] = v.z;
    t[lr][lc + j * 4 + 3] = v.w;
  }
  __syncthreads();
  ushort out[16];
  #pragma unroll
  for (int j = 0; j < 16; ++j)
    out[j] = f2bf(t[lc + j][lr]);
  ushort* dp = dst + (size_t)(c0 + lr) * R + r0 + lc;
  *(uint4*)dp = *(const uint4*)&out[0];
  *(uint4*)(dp + 8) = *(const uint4*)&out[8];
}

__global__ __launch_bounds__(256) void prep(
    const float* __restrict__ x, const float* __restrict__ wqkv,
    const float* __restrict__ wo, ushort* __restrict__ xb,
    ushort* __restrict__ wqkvT, ushort* __restrict__ woT) {
  __shared__ float t[64][65];
  const int bid = blockIdx.x;
  const int tid = threadIdx.x;
  if (bid < 4096) {
    const int i = bid * 256 + tid;
    float4 v = *(const float4*)(x + (size_t)i * 4);
    ushort4 o;
    o.x = f2bf(v.x); o.y = f2bf(v.y); o.z = f2bf(v.z); o.w = f2bf(v.w);
    *(ushort4*)(xb + (size_t)i * 4) = o;
  } else if (bid < 4096 + 768) {
    const int b2 = bid - 4096;             // wqkv: 1024 x 3072 -> 48 x 16 tiles
    const int bx = b2 % 48, by = b2 / 48;
    transpose_tile(wqkv, wqkvT, DMODEL, 3 * DMODEL, by * 64, bx * 64, t, tid);
  } else {
    const int b3 = bid - 4096 - 768;       // wo: 1024 x 1024 -> 16 x 16 tiles
    const int bx = b3 % 16, by = b3 / 16;
    transpose_tile(wo, woT, DMODEL, DMODEL, by * 64, bx * 64, t, tid);
  }
}

// ---------------------------------------------------------------------------
// 128x128 2-phase swizzled GEMM (round-7 proven; round-9 measured optimum).
// ---------------------------------------------------------------------------
template <bool OUT_BF16>
__global__ __launch_bounds__(256) void gemm_swz(
    const ushort* __restrict__ A, const ushort* __restrict__ Bt,
    void* __restrict__ Cv, int M, int N, int K, int relu_limit) {
  __shared__ ushort Asm[128 * 64];
  __shared__ ushort Bsm[128 * 64];

  const int tid  = threadIdx.x;
  const int lane = tid & 63;
  const int w    = tid >> 6;
  const int wr   = w >> 1, wc = w & 1;
  const int brow = blockIdx.y * 128;
  const int bcol = blockIdx.x * 128;

  f32x4 acc[4][4];
  #pragma unroll
  for (int i = 0; i < 4; ++i)
    #pragma unroll
    for (int j = 0; j < 4; ++j) acc[i][j] = (f32x4)0.f;

  const int r8   = lane >> 3;
  const int arow = w * 32 + r8;
  const int acol = ((lane & 7) ^ r8) * 8;   // pre-swizzled global source col
  const ushort* Ag = A  + (size_t)(brow + arow) * K + acol;
  const ushort* Bg = Bt + (size_t)(bcol + arow) * K + acol;

  const int l15 = lane & 15;
  const int khi = (lane >> 4) * 8;

  for (int k0 = 0; k0 < K; k0 += 64) {
    #pragma unroll
    for (int u = 0; u < 4; ++u) {
      gload_lds16(Ag + k0 + (size_t)u * 8 * K, &Asm[(w * 4 + u) * 512]);
      gload_lds16(Bg + k0 + (size_t)u * 8 * K, &Bsm[(w * 4 + u) * 512]);
    }
    __syncthreads();
    #pragma unroll
    for (int kk = 0; kk < 2; ++kk) {
      const int ko = kk * 32 + khi;
      bf16x8 af[4], bfr[4];
      #pragma unroll
      for (int mi = 0; mi < 4; ++mi) {
        const int row = wr * 64 + mi * 16 + l15;
        af[mi] = *(const bf16x8*)&Asm[row * 64 + (ko ^ ((row & 7) << 3))];
      }
      #pragma unroll
      for (int ni = 0; ni < 4; ++ni) {
        const int row = wc * 64 + ni * 16 + l15;
        bfr[ni] = *(const bf16x8*)&Bsm[row * 64 + (ko ^ ((row & 7) << 3))];
      }
      #pragma unroll
      for (int mi = 0; mi < 4; ++mi)
        #pragma unroll
        for (int ni = 0; ni < 4; ++ni)
          acc[mi][ni] = __builtin_amdgcn_mfma_f32_16x16x32_bf16(
              af[mi], bfr[ni], acc[mi][ni], 0, 0, 0);
    }
    __syncthreads();
  }

  #pragma unroll
  for (int mi = 0; mi < 4; ++mi) {
    #pragma unroll
    for (int ni = 0; ni < 4; ++ni) {
      const int r0  = brow + wr * 64 + mi * 16 + (lane >> 4) * 4;
      const int col = bcol + wc * 64 + ni * 16 + l15;
      const bool rl = col < relu_limit;
      #pragma unroll
      for (int i = 0; i < 4; ++i) {
        float v = acc[mi][ni][i];
        if (rl) v = fmaxf(v, 0.f);
        if (OUT_BF16)
          ((ushort*)Cv)[(size_t)(r0 + i) * N + col] = f2bf(v);
        else
          ((float*)Cv)[(size_t)(r0 + i) * N + col] = v;
      }
    }
  }
}

// ---------------------------------------------------------------------------
// Kernel A (MFMA): state[bh,c] = { KVT[e][d] = sum_t V[t][e] K[t][d], ksum[d] }
// state bf16.
// ---------------------------------------------------------------------------
__global__ __launch_bounds__(256) void chunk_sums_mfma(
    const ushort* __restrict__ qkvb, ushort* __restrict__ state) {
  __shared__ ushort Kt[64 * LP];   // Kt[d][t]
  __shared__ ushort Vt[64 * LP];   // Vt[e][t]

  const int bh = blockIdx.x >> 5;
  const int c  = blockIdx.x & (NC - 1);
  const int b  = bh >> 4;
  const int h  = bh & (NHEADS - 1);
  const int tid = threadIdx.x;

  const size_t rs   = 3 * DMODEL;
  const size_t base = ((size_t)(b * SEQ + c * CS)) * rs + (size_t)h * HD;

  const int r  = tid >> 2;          // timestep row 0..63
  const int sg = (tid & 3) * 16;    // col segment
  {
    const ushort* src = qkvb + base + (size_t)r * rs + sg;
    ushort8 k0 = *(const ushort8*)(src + DMODEL);
    ushort8 k1 = *(const ushort8*)(src + DMODEL + 8);
    ushort8 v0 = *(const ushort8*)(src + 2 * DMODEL);
    ushort8 v1 = *(const ushort8*)(src + 2 * DMODEL + 8);
    #pragma unroll
    for (int j = 0; j < 8; ++j) {
      Kt[(sg + j) * LP + r]     = k0[j];
      Kt[(sg + 8 + j) * LP + r] = k1[j];
      Vt[(sg + j) * LP + r]     = v0[j];
      Vt[(sg + 8 + j) * LP + r] = v1[j];
    }
  }
  __syncthreads();

  const int lane = tid & 63;
  const int w    = tid >> 6;
  const int l15  = lane & 15;
  const int khi  = (lane >> 4) * 8;

  bf16x8 va[2];
  #pragma unroll
  for (int kk = 0; kk < 2; ++kk)
    va[kk] = *(const bf16x8*)&Vt[(w * 16 + l15) * LP + kk * 32 + khi];

  f32x4 a[4];
  #pragma unroll
  for (int ct = 0; ct < 4; ++ct) {
    a[ct] = (f32x4)0.f;
    #pragma unroll
    for (int kk = 0; kk < 2; ++kk)
      a[ct] = __builtin_amdgcn_mfma_f32_16x16x32_bf16(
          va[kk], *(const bf16x8*)&Kt[(ct * 16 + l15) * LP + kk * 32 + khi],
          a[ct], 0, 0, 0);
  }

  ushort* st = state + (size_t)blockIdx.x * STSZ;
  #pragma unroll
  for (int ct = 0; ct < 4; ++ct) {
    #pragma unroll
    for (int i = 0; i < 4; ++i) {
      const int e = w * 16 + (lane >> 4) * 4 + i;
      const int d = ct * 16 + l15;
      st[e * HD + d] = f2bf(a[ct][i]);
    }
  }

  if (tid < HD) {
    float s = 0.f;
    #pragma unroll 8
    for (int t = 0; t < CS; ++t) s += bf2f(Kt[tid * LP + t]);
    st[HD * HD + tid] = f2bf(s);
  }
}

// ---------------------------------------------------------------------------
// Kernel B: exclusive prefix over chunks, element-parallel. bf16 in/out,
// f32 running accumulator.
// ---------------------------------------------------------------------------
__global__ __launch_bounds__(256) void chunk_prefix(ushort* __restrict__ state) {
  const int g = blockIdx.x * 256 + threadIdx.x;
  const int total = 2 * NHEADS * STSZ;
  if (g >= total) return;
  const int bh   = g / STSZ;
  const int elem = g - bh * STSZ;
  ushort* p = state + (size_t)bh * NC * STSZ + elem;

  float run = 0.f;
  #pragma unroll
  for (int c = 0; c < NC; ++c) {
    const float t = bf2f(p[(size_t)c * STSZ]);
    p[(size_t)c * STSZ] = f2bf(run);
    run += t;
  }
}

// ---------------------------------------------------------------------------
// Kernel C (MFMA): per-(b,h,chunk) output, writes y bf16. state bf16.
// ---------------------------------------------------------------------------
__global__ __launch_bounds__(256) void chunk_out_mfma(
    const ushort* __restrict__ qkvb, const ushort* __restrict__ state,
    ushort* __restrict__ y) {
  __shared__ ushort Qs[64 * LP];   // Q[t][d]
  __shared__ ushort Ks[64 * LP];   // K[s][d]
  __shared__ ushort Vt[80 * LP];   // Vaug^T[n][s]: n<64 = V[s][n], n=64: ones
  __shared__ ushort Kv[80 * LP];   // KvAug^T[n][d]: n<64 = KVp[d][n], n=64: ksum
  __shared__ ushort Sm[64 * LP];   // masked S[t][s] bf16

  const int bh = blockIdx.x >> 5;
  const int c  = blockIdx.x & (NC - 1);
  const int b  = bh >> 4;
  const int h  = bh & (NHEADS - 1);
  const int tid = threadIdx.x;

  const size_t rs   = 3 * DMODEL;
  const size_t base = ((size_t)(b * SEQ + c * CS)) * rs + (size_t)h * HD;

  {
    const int r  = tid >> 2;
    const int sg = (tid & 3) * 16;
    const ushort* src = qkvb + base + (size_t)r * rs + sg;
    ushort8 q0 = *(const ushort8*)(src);
    ushort8 q1 = *(const ushort8*)(src + 8);
    ushort8 k0 = *(const ushort8*)(src + DMODEL);
    ushort8 k1 = *(const ushort8*)(src + DMODEL + 8);
    ushort8 v0 = *(const ushort8*)(src + 2 * DMODEL);
    ushort8 v1 = *(const ushort8*)(src + 2 * DMODEL + 8);
    *(ushort8*)&Qs[r * LP + sg]     = q0;
    *(ushort8*)&Qs[r * LP + sg + 8] = q1;
    *(ushort8*)&Ks[r * LP + sg]     = k0;
    *(ushort8*)&Ks[r * LP + sg + 8] = k1;
    #pragma unroll
    for (int j = 0; j < 8; ++j) {
      Vt[(sg + j) * LP + r]     = v0[j];
      Vt[(sg + 8 + j) * LP + r] = v1[j];
    }
  }
  // Vt rows 64..79: row 64 = 1.0, rest 0
  {
    const int idx = tid * 4;                 // 0..1023
    const int row = 64 + (idx >> 6);
    const int col = idx & 63;
    const ushort val = (row == 64) ? (ushort)0x3F80 : (ushort)0;
    ushort4 v4 = {val, val, val, val};
    *(ushort4*)&Vt[row * LP + col] = v4;
  }
  // Kv rows 0..63 direct bf16 copy; row 64 = ksum; rows 65..79 = 0
  {
    const ushort* sp = state + ((size_t)bh * NC + c) * STSZ;
    const int off = tid * 16;                // 0..4095
    const int e   = off >> 6;
    const int col = off & 63;
    *(ushort8*)&Kv[e * LP + col]     = *(const ushort8*)(sp + off);
    *(ushort8*)&Kv[e * LP + col + 8] = *(const ushort8*)(sp + off + 8);
    if (tid < 16) {
      const int c4 = tid * 4;
      *(ushort4*)&Kv[64 * LP + c4] = *(const ushort4*)(sp + HD * HD + c4);
    }
    if (tid < 240) {
      const int idx = tid * 4;               // 0..959
      const int row = 65 + (idx >> 6);
      const int col2 = idx & 63;
      ushort4 z = {0, 0, 0, 0};
      *(ushort4*)&Kv[row * LP + col2] = z;
    }
  }
  __syncthreads();

  const int lane = tid & 63;
  const int w    = tid >> 6;
  const int l15  = lane & 15;
  const int khi  = (lane >> 4) * 8;

  // ---- S = Q K^T for row stripe w*16..w*16+15 ----
  bf16x8 qa[2];
  #pragma unroll
  for (int kk = 0; kk < 2; ++kk)
    qa[kk] = *(const bf16x8*)&Qs[(w * 16 + l15) * LP + kk * 32 + khi];

  {
    f32x4 sac[4];
    #pragma unroll
    for (int ct = 0; ct < 4; ++ct) {
      sac[ct] = (f32x4)0.f;
      #pragma unroll
      for (int kk = 0; kk < 2; ++kk)
        sac[ct] = __builtin_amdgcn_mfma_f32_16x16x32_bf16(
            qa[kk], *(const bf16x8*)&Ks[(ct * 16 + l15) * LP + kk * 32 + khi],
            sac[ct], 0, 0, 0);
    }
    const int t0 = w * 16 + (lane >> 4) * 4;
    #pragma unroll
    for (int ct = 0; ct < 4; ++ct) {
      const int s = ct * 16 + l15;
      #pragma unroll
      for (int i = 0; i < 4; ++i) {
        const int t = t0 + i;
        const float v = (s <= t) ? sac[ct][i] : 0.f;
        Sm[t * LP + s] = f2bf(v);
      }
    }
  }
  __syncthreads();

  // ---- O = Q @ KvAug + Sm @ VtAug  (N = 80) ----
  bf16x8 sa[2];
  #pragma unroll
  for (int kk = 0; kk < 2; ++kk)
    sa[kk] = *(const bf16x8*)&Sm[(w * 16 + l15) * LP + kk * 32 + khi];

  f32x4 o[5];
  #pragma unroll
  for (int ct = 0; ct < 5; ++ct) {
    o[ct] = (f32x4)0.f;
    #pragma unroll
    for (int kk = 0; kk < 2; ++kk)
      o[ct] = __builtin_amdgcn_mfma_f32_16x16x32_bf16(
          qa[kk], *(const bf16x8*)&Kv[(ct * 16 + l15) * LP + kk * 32 + khi],
          o[ct], 0, 0, 0);
    #pragma unroll
    for (int kk = 0; kk < 2; ++kk)
      o[ct] = __builtin_amdgcn_mfma_f32_16x16x32_bf16(
          sa[kk], *(const bf16x8*)&Vt[(ct * 16 + l15) * LP + kk * 32 + khi],
          o[ct], 0, 0, 0);
  }

  // ---- epilogue: den broadcast within 16-lane group, write y ----
  float den[4];
  #pragma unroll
  for (int i = 0; i < 4; ++i)
    den[i] = __shfl(o[4][i], lane & 48) + EPS_LA;

  const int t0 = w * 16 + (lane >> 4) * 4;
  #pragma unroll
  for (int ct = 0; ct < 4; ++ct) {
    const int e = ct * 16 + l15;
    #pragma unroll
    for (int i = 0; i < 4; ++i) {
      const int t = t0 + i;
      y[((size_t)(b * SEQ + c * CS + t)) * DMODEL + (size_t)h * HD + e] =
          f2bf(o[ct][i] / den[i]);
    }
  }
}

// ---------------------------------------------------------------------------
extern "C" void kernel_launch(void* const* d_in, const int* in_sizes, int n_in,
                              void* d_out, int out_size, void* d_ws,
                              size_t ws_size, hipStream_t stream) {
  (void)in_sizes; (void)n_in; (void)out_size; (void)ws_size;
  const float* x    = (const float*)d_in[0];
  const float* wqkv = (const float*)d_in[1];
  const float* wo   = (const float*)d_in[2];
  float* out = (float*)d_out;

  const int M  = 2 * SEQ;     // 4096
  const int K  = DMODEL;      // 1024
  const int N1 = 3 * DMODEL;  // 3072
  const int N2 = DMODEL;      // 1024

  // workspace layout (~56 MiB)
  ushort* stateb = (ushort*)d_ws;                           // 8.125 MiB
  ushort* qkvb   = stateb + (size_t)2 * NHEADS * NC * STSZ; // 24 MiB
  ushort* xb     = qkvb + (size_t)M * N1;                   // 8 MiB
  ushort* yb     = xb + (size_t)M * K;                      // 8 MiB
  ushort* wqkvT  = yb + (size_t)M * K;                      // 6 MiB
  ushort* woT    = wqkvT + (size_t)K * N1;                  // 2 MiB

  dim3 blk(256);

  // fused prep: conv (4096 blocks) + wqkv transpose (768) + wo transpose (256)
  prep<<<dim3(4096 + 768 + 256), blk, 0, stream>>>(x, wqkv, wo, xb, wqkvT, woT);

  gemm_swz<true><<<dim3(N1 / 128, M / 128), blk, 0, stream>>>(
      xb, wqkvT, qkvb, M, N1, K, 2 * DMODEL);

  chunk_sums_mfma<<<dim3(2 * NHEADS * NC), blk, 0, stream>>>(qkvb, stateb);

  const int total = 2 * NHEADS * STSZ;
  chunk_prefix<<<dim3((total + 255) / 256), blk, 0, stream>>>(stateb);

  chunk_out_mfma<<<dim3(2 * NHEADS * NC), blk, 0, stream>>>(qkvb, stateb, yb);

  gemm_swz<false><<<dim3(N2 / 128, M / 128), blk, 0, stream>>>(
      yb, woT, out, M, N2, K, 0);
}